// Round 10
// baseline (569.301 us; speedup 1.0000x reference)
//
#include <hip/hip_runtime.h>

#define RR 48
#define GG 300
#define HW2 (GG * GG)
#define NPLANE (RR * HW2)
#define NVEC (RR * GG)
#define CC 27
#define NBUCK 32768  // 32^3 Morton buckets
#define TP 64        // points per block tile
#define FROW 148     // featT row stride in words: 16B-aligned rows, 37.9 KB total

// transpose geometry: 16-row x 256-pos tiles, 3 passes over R=48
#define TROWS 16
#define TCOLS 256
#define PCHUNK ((HW2 + TCOLS - 1) / TCOLS)  // 352 chunks (tail = 144 pos)
#define NPASS (RR / TROWS)                  // 3
#define TPB3 (3 * NPASS * PCHUNK)           // 3168 plane-transpose blocks
#define VBLK ((3 * NVEC + 255) / 256)       // 169 vec-transpose blocks
#define TROW2 260                           // LDS row stride (words), 16B-aligned

struct Axis { int i0, i1; float f; };

__device__ __forceinline__ Axis axis_interp(float x) {
  float g = x * 2.0f - 1.0f;
  float ih = (g + 1.0f) * 0.5f * (float)(GG - 1);
  int i0 = (int)floorf(ih);
  i0 = i0 < 0 ? 0 : (i0 > GG - 1 ? GG - 1 : i0);
  int i1 = i0 + 1 > GG - 1 ? GG - 1 : i0 + 1;
  Axis a; a.i0 = i0; a.i1 = i1; a.f = ih - (float)i0;
  return a;
}

// ---------------- sort machinery ----------------
__device__ __forceinline__ unsigned part3(unsigned v) {
  unsigned r = 0;
  r |= (v & 1u);
  r |= (v & 2u) << 2;
  r |= (v & 4u) << 4;
  r |= (v & 8u) << 6;
  r |= (v & 16u) << 8;
  return r;
}

__device__ __forceinline__ int morton_key(float x, float y, float z) {
  int qx = (int)(x * 32.0f); qx = qx < 0 ? 0 : (qx > 31 ? 31 : qx);
  int qy = (int)(y * 32.0f); qy = qy < 0 ? 0 : (qy > 31 ? 31 : qy);
  int qz = (int)(z * 32.0f); qz = qz < 0 ? 0 : (qz > 31 ? 31 : qz);
  return (int)(part3((unsigned)qx) | (part3((unsigned)qy) << 1) | (part3((unsigned)qz) << 2));
}

__global__ void __launch_bounds__(256) hist_kernel(const float* __restrict__ xyz, int n,
                                                   int* __restrict__ offs) {
  int i = blockIdx.x * blockDim.x + threadIdx.x;
  if (i >= n) return;
  atomicAdd(&offs[morton_key(xyz[i * 3], xyz[i * 3 + 1], xyz[i * 3 + 2])], 1);
}

__global__ void __launch_bounds__(1024) scan_kernel(int* __restrict__ offs) {
  __shared__ int part[1024];
  int t = threadIdx.x;
  int base = t * (NBUCK / 1024);
  int loc[NBUCK / 1024];
  int s = 0;
#pragma unroll
  for (int i = 0; i < NBUCK / 1024; ++i) { loc[i] = offs[base + i]; s += loc[i]; }
  part[t] = s;
  __syncthreads();
  for (int off = 1; off < 1024; off <<= 1) {
    int u = (t >= off) ? part[t - off] : 0;
    __syncthreads();
    part[t] += u;
    __syncthreads();
  }
  int excl = (t == 0) ? 0 : part[t - 1];
#pragma unroll
  for (int i = 0; i < NBUCK / 1024; ++i) {
    int c = loc[i];
    offs[base + i] = excl;
    excl += c;
  }
}

// ---------------- transpose bodies ----------
__device__ __forceinline__ void plane_transpose_vb(
    int vb, int t, float* __restrict__ tile,
    const float* __restrict__ p0, const float* __restrict__ p1, const float* __restrict__ p2,
    float* __restrict__ t0, float* __restrict__ t1, float* __restrict__ t2) {
  int rem = vb;
  int plane = rem / (NPASS * PCHUNK);
  rem -= plane * (NPASS * PCHUNK);
  int pass = rem / PCHUNK;
  int chunk = rem - pass * PCHUNK;
  const float* in = (plane == 0) ? p0 : (plane == 1) ? p1 : p2;
  float* outp = (plane == 0) ? t0 : (plane == 1) ? t1 : t2;
  int base = chunk * TCOLS;
  int rbase = pass * TROWS;

  int p4 = t & 63;
  int rg = t >> 6;
#pragma unroll
  for (int i = 0; i < TROWS / 4; ++i) {
    int r = i * 4 + rg;
    int pos = base + p4 * 4;
    if (pos < HW2) {
      float4 v = *(const float4*)(in + (size_t)(rbase + r) * HW2 + pos);
      *(float4*)&tile[r * TROW2 + p4 * 4] = v;
    }
  }
  __syncthreads();

  int c4 = t & 3;
  int hwl = t >> 2;
#pragma unroll
  for (int jj = 0; jj < 4; ++jj) {
    int hw = jj * 64 + hwl;
    if (base + hw < HW2) {
      float4 w;
      w.x = tile[(c4 * 4 + 0) * TROW2 + hw];
      w.y = tile[(c4 * 4 + 1) * TROW2 + hw];
      w.z = tile[(c4 * 4 + 2) * TROW2 + hw];
      w.w = tile[(c4 * 4 + 3) * TROW2 + hw];
      *(float4*)(outp + (size_t)(base + hw) * RR + rbase + c4 * 4) = w;
    }
  }
}

__device__ __forceinline__ void vec_transpose_e(
    int e, const float* __restrict__ v0, const float* __restrict__ v1,
    const float* __restrict__ v2, float* __restrict__ tv0,
    float* __restrict__ tv1, float* __restrict__ tv2) {
  if (e < 3 * NVEC) {
    int v = e / NVEC;
    int rem = e - v * NVEC;
    int i = rem / RR;
    int r = rem - i * RR;
    const float* in = (v == 0) ? v0 : (v == 1) ? v1 : v2;
    float* out = (v == 0) ? tv0 : (v == 1) ? tv1 : tv2;
    out[i * RR + r] = in[r * GG + i];
  }
}

// merged: scatter || plane transposes || vec transposes (round-5 proven)
__global__ void __launch_bounds__(256) trans_scatter_kernel(
    const float* __restrict__ xyz, int n, int* __restrict__ offs,
    int* __restrict__ sidx, float4* __restrict__ sxyz, int scb,
    const float* __restrict__ p0, const float* __restrict__ p1, const float* __restrict__ p2,
    float* __restrict__ t0, float* __restrict__ t1, float* __restrict__ t2,
    const float* __restrict__ v0, const float* __restrict__ v1, const float* __restrict__ v2,
    float* __restrict__ tv0, float* __restrict__ tv1, float* __restrict__ tv2) {
  __shared__ float tile[TROWS * TROW2];
  int bb = blockIdx.x;
  int t = threadIdx.x;

  if (bb < scb) {
    int i = bb * 256 + t;
    if (i < n) {
      float x = xyz[i * 3], y = xyz[i * 3 + 1], z = xyz[i * 3 + 2];
      int key = morton_key(x, y, z);
      int pos = atomicAdd(&offs[key], 1);
      if (sxyz) sxyz[pos] = make_float4(x, y, z, __int_as_float(i));
      else      sidx[pos] = i;
    }
  } else if (bb < scb + TPB3) {
    plane_transpose_vb(bb - scb, t, tile, p0, p1, p2, t0, t1, t2);
  } else {
    vec_transpose_e((bb - scb - TPB3) * 256 + t, v0, v1, v2, tv0, tv1, tv2);
  }
}

// ---------------- fused main ----------------
// featT layout: [point][channel] = [TP][FROW] so both LDS sides are b128:
// phase 1 writes one float4 per gather_seg; phase 2 reads float4 along k.
__device__ __forceinline__ void gather_seg(const float* __restrict__ P, Axis ai, Axis aj,
                                           const float* __restrict__ V, Axis ak,
                                           int r4, float* __restrict__ dst) {
  float fi = ai.f, fj = aj.f, fk = ak.f;
  float w00 = (1.f - fi) * (1.f - fj);
  float w01 = (1.f - fi) * fj;
  float w10 = fi * (1.f - fj);
  float w11 = fi * fj;
  float omk = 1.f - fk;
  float4 q00 = *(const float4*)(P + (ai.i0 * GG + aj.i0) * RR + r4);
  float4 q01 = *(const float4*)(P + (ai.i0 * GG + aj.i1) * RR + r4);
  float4 q10 = *(const float4*)(P + (ai.i1 * GG + aj.i0) * RR + r4);
  float4 q11 = *(const float4*)(P + (ai.i1 * GG + aj.i1) * RR + r4);
  float4 b0 = *(const float4*)(V + ak.i0 * RR + r4);
  float4 b1 = *(const float4*)(V + ak.i1 * RR + r4);
  float4 o;
  o.x = (w00 * q00.x + w01 * q01.x + w10 * q10.x + w11 * q11.x) * (omk * b0.x + fk * b1.x);
  o.y = (w00 * q00.y + w01 * q01.y + w10 * q10.y + w11 * q11.y) * (omk * b0.y + fk * b1.y);
  o.z = (w00 * q00.z + w01 * q01.z + w10 * q10.z + w11 * q11.z) * (omk * b0.z + fk * b1.z);
  o.w = (w00 * q00.w + w01 * q01.w + w10 * q10.w + w11 * q11.w) * (omk * b0.w + fk * b1.w);
  *(float4*)(dst + r4) = o;  // one ds_write_b128 (16B-aligned: dst,r4 mult of 4 words)
}

// 512 threads / 8 waves per block, same TP=64 tile: 38 KB LDS -> 4 blocks/CU
// -> 32 waves/CU (full occupancy; round-9 was 16). Phase 2: 8 threads/point,
// wave-uniform q keeps F in SGPRs (round-2 lesson).
__global__ void __launch_bounds__(512, 8) tensorf_fused(
    const float4* __restrict__ sxyz, const int* __restrict__ sidx,
    const float* __restrict__ xyz,
    const float* __restrict__ Txy, const float* __restrict__ Txz, const float* __restrict__ Tyz,
    const float* __restrict__ Tx, const float* __restrict__ Ty, const float* __restrict__ Tz,
    const float* __restrict__ F, float* __restrict__ out, int n, int chunkLen) {
  __shared__ float featT[TP * FROW];  // 37.9 KB
  __shared__ int oiS[TP];
  int b = blockIdx.x;
  int nb = (b & 7) * chunkLen + (b >> 3);  // XCD-aware: each XCD streams one Morton chunk
  int base = nb * TP;
  int tid = threadIdx.x;
  int g = tid >> 4;   // group 0..31, one point per group per iter
  int l = tid & 15;   // lane within group; lanes 0..11 do the loads

  // ---- phase 1: coalesced gather + interpolate -> featT[TP][144] ----
#pragma unroll 1
  for (int it = 0; it < TP / 32; ++it) {
    int pl = (it << 5) + g;
    int sp = base + pl;
    if (sp < n) {
      float x, y, z;
      int oi;
      if (sxyz) {
        float4 p4 = sxyz[sp];  // coalesced sorted records
        x = p4.x; y = p4.y; z = p4.z;
        oi = __float_as_int(p4.w);
      } else {
        oi = sidx[sp];
        x = xyz[oi * 3 + 0];
        y = xyz[oi * 3 + 1];
        z = xyz[oi * 3 + 2];
      }
      if (l == 12) oiS[pl] = oi;
      Axis ax = axis_interp(x), ay = axis_interp(y), az = axis_interp(z);
      if (l < 12) {
        int r4 = l << 2;
        float* dst = &featT[pl * FROW];
        gather_seg(Txy, ax, ay, Tz, az, r4, dst + 0 * RR);
        gather_seg(Txz, ax, az, Ty, ay, r4, dst + 1 * RR);
        gather_seg(Tyz, ay, az, Tx, ax, r4, dst + 2 * RR);
      }
    }
  }
  __syncthreads();

  // ---- phase 2: feat[144] @ F[144][27], 8 threads per point ----
  // q wave-uniform 0..7: q0..4 -> 4 ch at q*4; q5 -> ch 20..22 (3);
  // q6 -> ch 23..26 (4); q7 duplicates q6's compute, writes nothing.
  int p = tid & (TP - 1);
  int q = __builtin_amdgcn_readfirstlane(tid >> 6);  // wave-uniform 0..7
  int cbase = (q <= 5) ? q * 4 : 23;
  const float* Fh = F + cbase;
  const float* row = &featT[p * FROW];

  float acc[4];
#pragma unroll
  for (int c = 0; c < 4; ++c) acc[c] = 0.f;

#pragma unroll 4
  for (int k4 = 0; k4 < 36; ++k4) {
    float4 fv = *(const float4*)(row + 4 * k4);  // ds_read_b128
    const float* Fr = Fh + (k4 * 4) * CC;
#pragma unroll
    for (int c = 0; c < 4; ++c) {
      acc[c] = fmaf(fv.w, Fr[3 * CC + c],
               fmaf(fv.z, Fr[2 * CC + c],
               fmaf(fv.y, Fr[CC + c],
               fmaf(fv.x, Fr[c], acc[c]))));
    }
  }

  int sp = base + p;
  int nw = (q == 5) ? 3 : ((q == 7) ? 0 : 4);  // wave-uniform write count
  if (sp < n && nw > 0) {
    int oi = oiS[p];
    float* o = out + (size_t)oi * CC + cbase;
#pragma unroll
    for (int c = 0; c < 4; ++c)
      if (c < nw) o[c] = acc[c];
  }
}

// ---------------- fallback (no workspace) ----------------
__global__ void __launch_bounds__(256) tensorf_naive(
    const float* __restrict__ xyz,
    const float* __restrict__ Pxy, const float* __restrict__ Pxz, const float* __restrict__ Pyz,
    const float* __restrict__ Vx, const float* __restrict__ Vy, const float* __restrict__ Vz,
    const float* __restrict__ F, float* __restrict__ out, int n) {
  int idx = blockIdx.x * blockDim.x + threadIdx.x;
  if (idx >= n) return;
  float x = xyz[idx * 3], y = xyz[idx * 3 + 1], z = xyz[idx * 3 + 2];
  Axis ax = axis_interp(x), ay = axis_interp(y), az = axis_interp(z);
  float acc[CC];
#pragma unroll
  for (int c = 0; c < CC; ++c) acc[c] = 0.f;
  const float* Ps[3] = {Pxy, Pxz, Pyz};
  const float* Vs[3] = {Vz, Vy, Vx};
  Axis A[3][2] = {{ax, ay}, {ax, az}, {ay, az}};
  Axis K[3] = {az, ay, ax};
#pragma unroll 1
  for (int s = 0; s < 3; ++s) {
    Axis ai = A[s][0], aj = A[s][1], ak = K[s];
    float fi = ai.f, fj = aj.f, fk = ak.f;
    float w00 = (1.f - fi) * (1.f - fj), w01 = (1.f - fi) * fj;
    float w10 = fi * (1.f - fj), w11 = fi * fj, omk = 1.f - fk;
#pragma unroll 1
    for (int r = 0; r < RR; ++r) {
      const float* pr = Ps[s] + r * HW2;
      float ft = (w00 * pr[ai.i0 * GG + aj.i0] + w01 * pr[ai.i0 * GG + aj.i1] +
                  w10 * pr[ai.i1 * GG + aj.i0] + w11 * pr[ai.i1 * GG + aj.i1]) *
                 (omk * Vs[s][r * GG + ak.i0] + fk * Vs[s][r * GG + ak.i1]);
      const float* Fr = F + (s * RR + r) * CC;
#pragma unroll
      for (int c = 0; c < CC; ++c) acc[c] = fmaf(ft, Fr[c], acc[c]);
    }
  }
  float* o = out + (size_t)idx * CC;
#pragma unroll
  for (int c = 0; c < CC; ++c) o[c] = acc[c];
}

extern "C" void kernel_launch(void* const* d_in, const int* in_sizes, int n_in,
                              void* d_out, int out_size, void* d_ws, size_t ws_size,
                              hipStream_t stream) {
  const float* xyz = (const float*)d_in[0];
  const float* pxy = (const float*)d_in[1];
  const float* pxz = (const float*)d_in[2];
  const float* pyz = (const float*)d_in[3];
  const float* vx = (const float*)d_in[4];
  const float* vy = (const float*)d_in[5];
  const float* vz = (const float*)d_in[6];
  const float* F = (const float*)d_in[7];
  float* out = (float*)d_out;
  int n = in_sizes[0] / 3;
  int nblk = (n + 255) / 256;

  size_t fixed = (size_t)(3 * NPLANE + 3 * NVEC) * sizeof(float) +
                 (size_t)NBUCK * sizeof(int);
  size_t need1 = fixed + (size_t)n * sizeof(int);      // sorted-index variant
  size_t need2 = fixed + (size_t)n * sizeof(float4);   // sorted-record variant

  if (ws_size >= need1) {
    float* w = (float*)d_ws;
    float* Txy = w;
    float* Txz = Txy + NPLANE;
    float* Tyz = Txz + NPLANE;
    float* Tx = Tyz + NPLANE;
    float* Ty = Tx + NVEC;
    float* Tz = Ty + NVEC;
    int* offs = (int*)(Tz + NVEC);

    int* sidx = nullptr;
    float4* sxyz = nullptr;
    if (ws_size >= need2) sxyz = (float4*)(offs + NBUCK);
    else sidx = (int*)(offs + NBUCK);

    hipMemsetAsync(offs, 0, (size_t)NBUCK * sizeof(int), stream);
    // proven chain: hist -> scan -> [scatter || transposes] -> fused
    hist_kernel<<<nblk, 256, 0, stream>>>(xyz, n, offs);
    scan_kernel<<<1, 1024, 0, stream>>>(offs);
    trans_scatter_kernel<<<nblk + TPB3 + VBLK, 256, 0, stream>>>(
        xyz, n, offs, sidx, sxyz, nblk,
        pxy, pxz, pyz, Txy, Txz, Tyz, vx, vy, vz, Tx, Ty, Tz);

    int ntile = (n + TP - 1) / TP;
    int chunkLen = (ntile + 7) / 8;
    tensorf_fused<<<chunkLen * 8, 512, 0, stream>>>(sxyz, sidx, xyz, Txy, Txz, Tyz,
                                                    Tx, Ty, Tz, F, out, n, chunkLen);
  } else {
    tensorf_naive<<<nblk, 256, 0, stream>>>(xyz, pxy, pxz, pyz, vx, vy, vz, F, out, n);
  }
}

// Round 11
// 514.011 us; speedup vs baseline: 1.1076x; 1.1076x over previous
//
#include <hip/hip_runtime.h>

#define RR 48
#define GG 300
#define HW2 (GG * GG)
#define NPLANE (RR * HW2)
#define NVEC (RR * GG)
#define CC 27
#define TP 64        // points per block tile
#define FROW 148     // featT row stride in words: 16B-aligned rows, 37.9 KB total

// transpose geometry: 16-row x 256-pos tiles, 3 passes over R=48
#define TROWS 16
#define TCOLS 256
#define PCHUNK ((HW2 + TCOLS - 1) / TCOLS)  // 352 chunks (tail = 144 pos)
#define NPASS (RR / TROWS)                  // 3
#define TPB3 (3 * NPASS * PCHUNK)           // 3168 plane-transpose blocks
#define VBLK ((3 * NVEC + 255) / 256)       // 169 vec-transpose blocks
#define TROW2 260                           // LDS row stride (words), 16B-aligned

struct Axis { int i0, i1; float f; };

__device__ __forceinline__ Axis axis_interp(float x) {
  float g = x * 2.0f - 1.0f;
  float ih = (g + 1.0f) * 0.5f * (float)(GG - 1);
  int i0 = (int)floorf(ih);
  i0 = i0 < 0 ? 0 : (i0 > GG - 1 ? GG - 1 : i0);
  int i1 = i0 + 1 > GG - 1 ? GG - 1 : i0 + 1;
  Axis a; a.i0 = i0; a.i1 = i1; a.f = ih - (float)i0;
  return a;
}

// ---------------- transpose bodies ----------
__device__ __forceinline__ void plane_transpose_vb(
    int vb, int t, float* __restrict__ tile,
    const float* __restrict__ p0, const float* __restrict__ p1, const float* __restrict__ p2,
    float* __restrict__ t0, float* __restrict__ t1, float* __restrict__ t2) {
  int rem = vb;
  int plane = rem / (NPASS * PCHUNK);
  rem -= plane * (NPASS * PCHUNK);
  int pass = rem / PCHUNK;
  int chunk = rem - pass * PCHUNK;
  const float* in = (plane == 0) ? p0 : (plane == 1) ? p1 : p2;
  float* outp = (plane == 0) ? t0 : (plane == 1) ? t1 : t2;
  int base = chunk * TCOLS;
  int rbase = pass * TROWS;

  int p4 = t & 63;
  int rg = t >> 6;
#pragma unroll
  for (int i = 0; i < TROWS / 4; ++i) {
    int r = i * 4 + rg;
    int pos = base + p4 * 4;
    if (pos < HW2) {
      float4 v = *(const float4*)(in + (size_t)(rbase + r) * HW2 + pos);
      *(float4*)&tile[r * TROW2 + p4 * 4] = v;
    }
  }
  __syncthreads();

  int c4 = t & 3;
  int hwl = t >> 2;
#pragma unroll
  for (int jj = 0; jj < 4; ++jj) {
    int hw = jj * 64 + hwl;
    if (base + hw < HW2) {
      float4 w;
      w.x = tile[(c4 * 4 + 0) * TROW2 + hw];
      w.y = tile[(c4 * 4 + 1) * TROW2 + hw];
      w.z = tile[(c4 * 4 + 2) * TROW2 + hw];
      w.w = tile[(c4 * 4 + 3) * TROW2 + hw];
      *(float4*)(outp + (size_t)(base + hw) * RR + rbase + c4 * 4) = w;
    }
  }
}

__device__ __forceinline__ void vec_transpose_e(
    int e, const float* __restrict__ v0, const float* __restrict__ v1,
    const float* __restrict__ v2, float* __restrict__ tv0,
    float* __restrict__ tv1, float* __restrict__ tv2) {
  if (e < 3 * NVEC) {
    int v = e / NVEC;
    int rem = e - v * NVEC;
    int i = rem / RR;
    int r = rem - i * RR;
    const float* in = (v == 0) ? v0 : (v == 1) ? v1 : v2;
    float* out = (v == 0) ? tv0 : (v == 1) ? tv1 : tv2;
    out[i * RR + r] = in[r * GG + i];
  }
}

// plane transposes || vec transposes (no sort machinery anymore)
__global__ void __launch_bounds__(256) transpose_kernel(
    const float* __restrict__ p0, const float* __restrict__ p1, const float* __restrict__ p2,
    float* __restrict__ t0, float* __restrict__ t1, float* __restrict__ t2,
    const float* __restrict__ v0, const float* __restrict__ v1, const float* __restrict__ v2,
    float* __restrict__ tv0, float* __restrict__ tv1, float* __restrict__ tv2) {
  __shared__ float tile[TROWS * TROW2];
  int bb = blockIdx.x;
  int t = threadIdx.x;
  if (bb < TPB3) {
    plane_transpose_vb(bb, t, tile, p0, p1, p2, t0, t1, t2);
  } else {
    vec_transpose_e((bb - TPB3) * 256 + t, v0, v1, v2, tv0, tv1, tv2);
  }
}

// ---------------- fused main (UNSORTED original order) ----------------
// Reads: transposed planes gathered randomly -> served by L3 (124 MB < 256 MB).
// Writes: out rows in original order -> fully coalesced streaming (the round-10
// post-mortem showed random 108B writes were the ~1 TB/s effective-BW poison).
__device__ __forceinline__ void gather_seg(const float* __restrict__ P, Axis ai, Axis aj,
                                           const float* __restrict__ V, Axis ak,
                                           int r4, float* __restrict__ dst) {
  float fi = ai.f, fj = aj.f, fk = ak.f;
  float w00 = (1.f - fi) * (1.f - fj);
  float w01 = (1.f - fi) * fj;
  float w10 = fi * (1.f - fj);
  float w11 = fi * fj;
  float omk = 1.f - fk;
  float4 q00 = *(const float4*)(P + (ai.i0 * GG + aj.i0) * RR + r4);
  float4 q01 = *(const float4*)(P + (ai.i0 * GG + aj.i1) * RR + r4);
  float4 q10 = *(const float4*)(P + (ai.i1 * GG + aj.i0) * RR + r4);
  float4 q11 = *(const float4*)(P + (ai.i1 * GG + aj.i1) * RR + r4);
  float4 b0 = *(const float4*)(V + ak.i0 * RR + r4);
  float4 b1 = *(const float4*)(V + ak.i1 * RR + r4);
  float4 o;
  o.x = (w00 * q00.x + w01 * q01.x + w10 * q10.x + w11 * q11.x) * (omk * b0.x + fk * b1.x);
  o.y = (w00 * q00.y + w01 * q01.y + w10 * q10.y + w11 * q11.y) * (omk * b0.y + fk * b1.y);
  o.z = (w00 * q00.z + w01 * q01.z + w10 * q10.z + w11 * q11.z) * (omk * b0.z + fk * b1.z);
  o.w = (w00 * q00.w + w01 * q01.w + w10 * q10.w + w11 * q11.w) * (omk * b0.w + fk * b1.w);
  *(float4*)(dst + r4) = o;  // one ds_write_b128
}

__global__ void __launch_bounds__(256, 4) tensorf_fused(
    const float* __restrict__ xyz,
    const float* __restrict__ Txy, const float* __restrict__ Txz, const float* __restrict__ Tyz,
    const float* __restrict__ Tx, const float* __restrict__ Ty, const float* __restrict__ Tz,
    const float* __restrict__ F, float* __restrict__ out, int n) {
  __shared__ float featT[TP * FROW];  // 37.9 KB -> 4 blocks/CU
  int base = blockIdx.x * TP;
  int tid = threadIdx.x;
  int g = tid >> 4;   // group 0..15, one point per group per iter
  int l = tid & 15;   // lane within group; lanes 0..11 do the loads

  // ---- phase 1: gather + interpolate -> featT[TP][144] ----
#pragma unroll 1
  for (int it = 0; it < TP / 16; ++it) {
    int pl = (it << 4) + g;
    int sp = base + pl;
    if (sp < n) {
      float x = xyz[sp * 3 + 0];   // broadcast within group (L1)
      float y = xyz[sp * 3 + 1];
      float z = xyz[sp * 3 + 2];
      Axis ax = axis_interp(x), ay = axis_interp(y), az = axis_interp(z);
      if (l < 12) {
        int r4 = l << 2;
        float* dst = &featT[pl * FROW];
        gather_seg(Txy, ax, ay, Tz, az, r4, dst + 0 * RR);
        gather_seg(Txz, ax, az, Ty, ay, r4, dst + 1 * RR);
        gather_seg(Tyz, ay, az, Tx, ax, r4, dst + 2 * RR);
      }
    }
  }
  __syncthreads();

  // ---- phase 2: feat[144] @ F[144][27], 4 threads per point ----
  // q wave-uniform via readfirstlane -> F reads stay s_load broadcasts
  // (round-2 lesson). Output writes are CONTIGUOUS in original order.
  int p = tid & (TP - 1);
  int q = __builtin_amdgcn_readfirstlane(tid >> 6);  // wave-uniform 0..3
  int cbase = (q == 3) ? 20 : q * 7;  // q3 overlaps q2 at c20 to stay in-bounds
  const float* Fh = F + cbase;
  const float* row = &featT[p * FROW];

  float acc[7];
#pragma unroll
  for (int c = 0; c < 7; ++c) acc[c] = 0.f;

#pragma unroll 4
  for (int k4 = 0; k4 < 36; ++k4) {
    float4 fv = *(const float4*)(row + 4 * k4);  // ds_read_b128, conflict-free
    const float* Fr = Fh + (k4 * 4) * CC;
#pragma unroll
    for (int c = 0; c < 7; ++c) {
      acc[c] = fmaf(fv.w, Fr[3 * CC + c],
               fmaf(fv.z, Fr[2 * CC + c],
               fmaf(fv.y, Fr[CC + c],
               fmaf(fv.x, Fr[c], acc[c]))));
    }
  }

  int sp = base + p;
  if (sp < n) {
    float* o = out + (size_t)sp * CC + cbase;  // streaming, coalesced
    if (q != 3) o[0] = acc[0];  // q3's c==0 (channel 20) is q2's copy
#pragma unroll
    for (int c = 1; c < 7; ++c) o[c] = acc[c];
  }
}

// ---------------- fallback (no workspace) ----------------
__global__ void __launch_bounds__(256) tensorf_naive(
    const float* __restrict__ xyz,
    const float* __restrict__ Pxy, const float* __restrict__ Pxz, const float* __restrict__ Pyz,
    const float* __restrict__ Vx, const float* __restrict__ Vy, const float* __restrict__ Vz,
    const float* __restrict__ F, float* __restrict__ out, int n) {
  int idx = blockIdx.x * blockDim.x + threadIdx.x;
  if (idx >= n) return;
  float x = xyz[idx * 3], y = xyz[idx * 3 + 1], z = xyz[idx * 3 + 2];
  Axis ax = axis_interp(x), ay = axis_interp(y), az = axis_interp(z);
  float acc[CC];
#pragma unroll
  for (int c = 0; c < CC; ++c) acc[c] = 0.f;
  const float* Ps[3] = {Pxy, Pxz, Pyz};
  const float* Vs[3] = {Vz, Vy, Vx};
  Axis A[3][2] = {{ax, ay}, {ax, az}, {ay, az}};
  Axis K[3] = {az, ay, ax};
#pragma unroll 1
  for (int s = 0; s < 3; ++s) {
    Axis ai = A[s][0], aj = A[s][1], ak = K[s];
    float fi = ai.f, fj = aj.f, fk = ak.f;
    float w00 = (1.f - fi) * (1.f - fj), w01 = (1.f - fi) * fj;
    float w10 = fi * (1.f - fj), w11 = fi * fj, omk = 1.f - fk;
#pragma unroll 1
    for (int r = 0; r < RR; ++r) {
      const float* pr = Ps[s] + r * HW2;
      float ft = (w00 * pr[ai.i0 * GG + aj.i0] + w01 * pr[ai.i0 * GG + aj.i1] +
                  w10 * pr[ai.i1 * GG + aj.i0] + w11 * pr[ai.i1 * GG + aj.i1]) *
                 (omk * Vs[s][r * GG + ak.i0] + fk * Vs[s][r * GG + ak.i1]);
      const float* Fr = F + (s * RR + r) * CC;
#pragma unroll
      for (int c = 0; c < CC; ++c) acc[c] = fmaf(ft, Fr[c], acc[c]);
    }
  }
  float* o = out + (size_t)idx * CC;
#pragma unroll
  for (int c = 0; c < CC; ++c) o[c] = acc[c];
}

extern "C" void kernel_launch(void* const* d_in, const int* in_sizes, int n_in,
                              void* d_out, int out_size, void* d_ws, size_t ws_size,
                              hipStream_t stream) {
  const float* xyz = (const float*)d_in[0];
  const float* pxy = (const float*)d_in[1];
  const float* pxz = (const float*)d_in[2];
  const float* pyz = (const float*)d_in[3];
  const float* vx = (const float*)d_in[4];
  const float* vy = (const float*)d_in[5];
  const float* vz = (const float*)d_in[6];
  const float* F = (const float*)d_in[7];
  float* out = (float*)d_out;
  int n = in_sizes[0] / 3;
  int nblk = (n + 255) / 256;

  size_t need = (size_t)(3 * NPLANE + 3 * NVEC) * sizeof(float);

  if (ws_size >= need) {
    float* w = (float*)d_ws;
    float* Txy = w;
    float* Txz = Txy + NPLANE;
    float* Tyz = Txz + NPLANE;
    float* Tx = Tyz + NPLANE;
    float* Ty = Tx + NVEC;
    float* Tz = Ty + NVEC;

    transpose_kernel<<<TPB3 + VBLK, 256, 0, stream>>>(
        pxy, pxz, pyz, Txy, Txz, Tyz, vx, vy, vz, Tx, Ty, Tz);

    int ntile = (n + TP - 1) / TP;
    tensorf_fused<<<ntile, 256, 0, stream>>>(xyz, Txy, Txz, Tyz,
                                             Tx, Ty, Tz, F, out, n);
  } else {
    tensorf_naive<<<nblk, 256, 0, stream>>>(xyz, pxy, pxz, pyz, vx, vy, vz, F, out, n);
  }
}